// Round 1
// baseline (717.044 us; speedup 1.0000x reference)
//
#include <hip/hip_runtime.h>
#include <hip/hip_bf16.h>
#include <cstdint>
#include <cstddef>

#define NN   50000
#define EE   800000
#define ET_  (EE + NN)      // 850000 edges incl. self-loops
#define FIN  500
#define HID_ 160
#define NC_  20
#define GG   8

typedef __attribute__((ext_vector_type(8))) short ab8;   // 8 bf16 (4 VGPRs)
typedef __attribute__((ext_vector_type(4))) float f4;    // MFMA accumulator

static __device__ __forceinline__ unsigned short f2bf(float v) {
    union { float f; uint32_t u; } c; c.f = v;
    uint32_t r = c.u + 0x7FFFu + ((c.u >> 16) & 1u);  // RNE
    return (unsigned short)(r >> 16);
}

static __device__ __forceinline__ float2 bf2f2(uint32_t u) {
    // u holds bf16 pair (lo = even ch, hi = odd ch)
    union { uint32_t u; float f; } a, b;
    a.u = u << 16;
    b.u = u & 0xffff0000u;
    return make_float2(a.f, b.f);
}

static __device__ __forceinline__ int lbound_i(const int* arr, int n, int val) {
    int lo = 0, hi = n;
    while (lo < hi) { int mid = (lo + hi) >> 1; if (arr[mid] < val) lo = mid + 1; else hi = mid; }
    return lo;
}

// ---------------- CSR build ----------------
__global__ __launch_bounds__(256) void k_hist(const int* __restrict__ ei, int* __restrict__ deg) {
    int e = blockIdx.x * 256 + threadIdx.x;
    if (e >= ET_) return;
    int d = (e < EE) ? ei[EE + e] : (e - EE);
    atomicAdd(&deg[d], 1);
}

__global__ __launch_bounds__(256) void k_scan1(const int* __restrict__ deg, int* __restrict__ rowptr,
                                               int* __restrict__ bsum) {
    __shared__ int s[256];
    int t = threadIdx.x;
    int base = blockIdx.x * 1024 + t * 4;
    int v0 = (base + 0 < NN) ? deg[base + 0] : 0;
    int v1 = (base + 1 < NN) ? deg[base + 1] : 0;
    int v2 = (base + 2 < NN) ? deg[base + 2] : 0;
    int v3 = (base + 3 < NN) ? deg[base + 3] : 0;
    int tot = v0 + v1 + v2 + v3;
    s[t] = tot;
    __syncthreads();
    for (int off = 1; off < 256; off <<= 1) {
        int y = (t >= off) ? s[t - off] : 0;
        __syncthreads();
        s[t] += y;
        __syncthreads();
    }
    int excl = s[t] - tot;
    if (t == 255) bsum[blockIdx.x] = s[255];
    if (base + 0 < NN) rowptr[base + 0] = excl;  excl += v0;
    if (base + 1 < NN) rowptr[base + 1] = excl;  excl += v1;
    if (base + 2 < NN) rowptr[base + 2] = excl;  excl += v2;
    if (base + 3 < NN) rowptr[base + 3] = excl;
}

__global__ void k_scan2(int* __restrict__ bsum, int nb) {
    int t = threadIdx.x; // single wave of 64; nb <= 64
    int v = (t < nb) ? bsum[t] : 0;
    int orig = v;
    for (int off = 1; off < 64; off <<= 1) {
        int y = __shfl_up(v, off);
        if (t >= off) v += y;
    }
    if (t < nb) bsum[t] = v - orig; // exclusive prefix
}

__global__ __launch_bounds__(256) void k_scan3(int* __restrict__ rowptr, const int* __restrict__ bsum,
                                               int* __restrict__ cursor) {
    int i = blockIdx.x * 256 + threadIdx.x;
    if (i < NN) {
        int r = rowptr[i] + bsum[i >> 10];
        rowptr[i] = r;
        cursor[i] = r;
    }
    if (i == NN) rowptr[NN] = ET_;
}

__global__ __launch_bounds__(256) void k_scatter(const int* __restrict__ ei, int* __restrict__ cursor,
                                                 int2* __restrict__ epair) {
    int e = blockIdx.x * 256 + threadIdx.x;
    if (e >= ET_) return;
    int s, d;
    if (e < EE) { s = ei[e]; d = ei[EE + e]; } else { s = e - EE; d = e - EE; }
    int slot = atomicAdd(&cursor[d], 1);
    epair[slot] = make_int2(e, s);
}

// ---------------- weight prep: three weights in one launch (+ pooled zero) ----------------
// W[K,160] fp32 -> Wt[160,Kp] bf16 (transposed, zero-pad K)
__global__ __launch_bounds__(256) void k_prep_all(const float* __restrict__ W1, unsigned short* __restrict__ Wt1,
                                                  const float* __restrict__ W2, unsigned short* __restrict__ Wt2,
                                                  const float* __restrict__ Wm, unsigned short* __restrict__ Wmt,
                                                  float* __restrict__ pooled) {
    int idx = blockIdx.x * 256 + threadIdx.x;
    const int S1 = HID_ * 512, S2 = HID_ * HID_;
    if (idx < GG * HID_) pooled[idx] = 0.f;
    if (idx < S1) {
        int n = idx / 512, k = idx - n * 512;
        Wt1[idx] = (k < FIN) ? f2bf(W1[(size_t)k * HID_ + n]) : (unsigned short)0;
    } else if (idx < S1 + S2) {
        int j = idx - S1;
        int n = j / HID_, k = j - n * HID_;
        Wt2[j] = f2bf(W2[(size_t)k * HID_ + n]);
    } else if (idx < S1 + 2 * S2) {
        int j = idx - S1 - S2;
        int n = j / HID_, k = j - n * HID_;
        Wmt[j] = f2bf(Wm[(size_t)k * HID_ + n]);
    }
}

// ---------------- register-resident MFMA GEMM: C[M,160] = A[M,K] @ W[K,160] ----------------
// NO LDS, NO barriers. These GEMMs are latency-bound (K<=512, B is 50-160KB and
// L2-resident); staging through LDS with 2 barriers/k-step left every pipe <3% busy
// (measured: MfmaUtil 0.9%, Occupancy 3.8%). Instead:
//  - M-tile 64 per block (782 blocks), 4 waves, each wave owns 16 rows.
//  - A fragment: per-lane 16B ab8 straight from global (fp32->bf16 in-register for
//    layer 1), one-step prefetch.
//  - B fragment: per-MFMA 16B ab8 straight from global (L1/L2-served; each wave reads
//    the whole 50-160KB B once -> <=500MB of L2 traffic, ~15us at L2 BW, irrelevant).
// Fused epilogues preserved:
//  - asrc/adst -> als/ald: per-row per-head attention dots (GAT layers)
//  - batch+pooled: global mean-pool partial sums (readout GEMM)
template<int ABF>
static __device__ __forceinline__ void gemm_body(const void* __restrict__ Av,
                                                 const unsigned short* __restrict__ Bt,
                                                 float* __restrict__ C, __hip_bfloat16* __restrict__ Cb,
                                                 int M, int K, int Kp,
                                                 const float* __restrict__ bias, int act,
                                                 const float* __restrict__ asrc, const float* __restrict__ adst,
                                                 float* __restrict__ als_o, float* __restrict__ ald_o,
                                                 const int* __restrict__ batch_p, float* __restrict__ pooled) {
    int tid  = threadIdx.x;
    int lane = tid & 63;
    int w    = tid >> 6;
    int fr   = lane & 15;        // fragment row/col index
    int q    = lane >> 4;        // quad: k-subtile for inputs, row-subtile for output
    int row0 = blockIdx.x * 64;
    int arow = row0 + w * 16 + fr;   // row whose A-fragment this lane supplies
    bool rv  = arow < M;

    f4 acc[10];
#pragma unroll
    for (int t = 0; t < 10; t++) acc[t] = (f4)0.f;

    const int nk = Kp >> 5;
    const unsigned short* bbase = Bt + (size_t)fr * Kp + q * 8;

    auto loadA = [&](int s) -> ab8 {
        ab8 a = (ab8)0;
        int k0 = s * 32 + q * 8;
        if (ABF) {
            const unsigned short* Ab = (const unsigned short*)Av;
            if (rv) a = *reinterpret_cast<const ab8*>(&Ab[(size_t)arow * K + k0]);
        } else {
            const float* A = (const float*)Av;
            if (rv && k0 + 8 <= K) {
                const float4* s4 = reinterpret_cast<const float4*>(&A[(size_t)arow * K + k0]);
                float4 u = s4[0], v = s4[1];
                unsigned short pk[8] = {f2bf(u.x), f2bf(u.y), f2bf(u.z), f2bf(u.w),
                                        f2bf(v.x), f2bf(v.y), f2bf(v.z), f2bf(v.w)};
                a = *reinterpret_cast<ab8*>(pk);
            } else if (rv && k0 < K) {
                unsigned short pk[8];
#pragma unroll
                for (int c = 0; c < 8; c++)
                    pk[c] = (k0 + c < K) ? f2bf(A[(size_t)arow * K + k0 + c]) : (unsigned short)0;
                a = *reinterpret_cast<ab8*>(pk);
            }
        }
        return a;
    };

    ab8 acur = loadA(0);
    for (int s = 0; s < nk; s++) {
        ab8 anx = (ab8)0;
        if (s + 1 < nk) anx = loadA(s + 1);      // prefetch next A frag under this step's MFMAs
        const unsigned short* bp = bbase + (size_t)s * 32;
#pragma unroll
        for (int t = 0; t < 10; t++) {
            ab8 b = *reinterpret_cast<const ab8*>(&bp[(size_t)t * 16 * Kp]);
            acc[t] = __builtin_amdgcn_mfma_f32_16x16x32_bf16(acur, b, acc[t], 0, 0, 0);
        }
        acur = anx;
    }

    // ---- fused per-node attention dots: als/ald (GAT layers) ----
    if (als_o) {
        float av_s[10], av_d[10];
#pragma unroll
        for (int t = 0; t < 10; t++) { av_s[t] = asrc[t * 16 + fr]; av_d[t] = adst[t * 16 + fr]; }
#pragma unroll
        for (int i = 0; i < 4; i++) {
            int r = row0 + w * 16 + q * 4 + i;
            float ps[5], pd[5];
#pragma unroll
            for (int h = 0; h < 5; h++) {
                ps[h] = acc[2 * h][i] * av_s[2 * h] + acc[2 * h + 1][i] * av_s[2 * h + 1];
                pd[h] = acc[2 * h][i] * av_d[2 * h] + acc[2 * h + 1][i] * av_d[2 * h + 1];
            }
#pragma unroll
            for (int off = 8; off >= 1; off >>= 1)
#pragma unroll
                for (int h = 0; h < 5; h++) {
                    ps[h] += __shfl_xor(ps[h], off);
                    pd[h] += __shfl_xor(pd[h], off);
                }
            if (fr == 0 && r < M) {
#pragma unroll
                for (int h = 0; h < 5; h++) {
                    als_o[(size_t)r * 5 + h] = ps[h];
                    ald_o[(size_t)r * 5 + h] = pd[h];
                }
            }
        }
    }

    // ---- pool setup (readout GEMM): block-uniform-graph fast path ----
    int gu = -2;
    if (pooled) {
        int rhi = row0 + 63; if (rhi >= M) rhi = M - 1;
        int gl = batch_p[row0], gh = batch_p[rhi];
        gu = (gl == gh) ? gl : -1;
    }
    float psum[10];
#pragma unroll
    for (int t = 0; t < 10; t++) psum[t] = 0.f;

    // ---- epilogue: C/D layout col=lane&15, row=(lane>>4)*4+reg ----
    int rbase = row0 + w * 16 + q * 4;
#pragma unroll
    for (int t = 0; t < 10; t++) {
        int col = t * 16 + fr;
        float bv = bias ? bias[col] : 0.f;
#pragma unroll
        for (int i = 0; i < 4; i++) {
            int r = rbase + i;
            float v = acc[t][i] + bv;
            if (act) v = v > 0.f ? v : 0.01f * v;
            if (r < M) {
                if (C)  C[(size_t)r * HID_ + col] = v;
                if (Cb) *reinterpret_cast<unsigned short*>(&Cb[(size_t)r * HID_ + col]) = f2bf(v);
                if (gu >= 0) psum[t] += v;
                else if (gu == -1) atomicAdd(&pooled[batch_p[r] * HID_ + col], v);
            }
        }
    }
    if (gu >= 0) {
#pragma unroll
        for (int t = 0; t < 10; t++) {
            psum[t] += __shfl_xor(psum[t], 16);
            psum[t] += __shfl_xor(psum[t], 32);
        }
        if (q == 0) {
#pragma unroll
            for (int t = 0; t < 10; t++)
                atomicAdd(&pooled[gu * HID_ + t * 16 + fr], psum[t]);
        }
    }
}

__global__ __launch_bounds__(256) void k_gemm_f32(const void* __restrict__ Av,
                                                  const unsigned short* __restrict__ Bt,
                                                  float* __restrict__ C, __hip_bfloat16* __restrict__ Cb,
                                                  int M, int K, int Kp,
                                                  const float* __restrict__ bias, int act,
                                                  const float* __restrict__ asrc, const float* __restrict__ adst,
                                                  float* __restrict__ als_o, float* __restrict__ ald_o,
                                                  const int* __restrict__ batch_p, float* __restrict__ pooled) {
    gemm_body<0>(Av, Bt, C, Cb, M, K, Kp, bias, act, asrc, adst, als_o, ald_o, batch_p, pooled);
}

__global__ __launch_bounds__(256) void k_gemm_bf16(const void* __restrict__ Av,
                                                   const unsigned short* __restrict__ Bt,
                                                   float* __restrict__ C, __hip_bfloat16* __restrict__ Cb,
                                                   int M, int K, int Kp,
                                                   const float* __restrict__ bias, int act,
                                                   const float* __restrict__ asrc, const float* __restrict__ adst,
                                                   float* __restrict__ als_o, float* __restrict__ ald_o,
                                                   const int* __restrict__ batch_p, float* __restrict__ pooled) {
    gemm_body<1>(Av, Bt, C, Cb, M, K, Kp, bias, act, asrc, adst, als_o, ald_o, batch_p, pooled);
}

// ---------- fused edge softmax + aggregation + bias + leaky + LayerNorm ----------
// One wave per destination node. Channel map: lane l owns ch {2l,2l+1}; lanes 0..15
// additionally own {128+2l,128+2l+1} (head 4). 4B ushort2 gathers (2 loads/edge).
__global__ __launch_bounds__(256) void k_att_agg(const int* __restrict__ rowptr,
                                                 const int2* __restrict__ epair,
                                                 const float* __restrict__ als, const float* __restrict__ ald,
                                                 const __hip_bfloat16* __restrict__ hmat,
                                                 float* __restrict__ alphap,      // [ET_*5] overflow scratch
                                                 float* __restrict__ alpha_out,   // [ET_*5] edge-id order
                                                 const float* __restrict__ bias,
                                                 const float* __restrict__ lns, const float* __restrict__ lnb,
                                                 __hip_bfloat16* __restrict__ outb) {
    __shared__ float sExp[4][64 * 5];
    __shared__ int2  sPair[4][64];
    int wv   = threadIdx.x >> 6;
    int lane = threadIdx.x & 63;
    int node = blockIdx.x * 4 + wv;
    if (node >= NN) return;
    int start = rowptr[node], end = rowptr[node + 1];
    int deg = end - start;
    bool fits = (deg <= 64);
    float ad[5];
#pragma unroll
    for (int h = 0; h < 5; h++) ad[h] = ald[node * 5 + h];

    // ---- pass 1: exp(leaky(logit)), lane-parallel over edges ----
    float sm[5] = {0.f, 0.f, 0.f, 0.f, 0.f};
    for (int j = start + lane; j < end; j += 64) {
        int2 p = epair[j];
        const float* as = &als[(size_t)p.y * 5];
        int idx = j - start;
        if (fits) sPair[wv][idx] = p;
#pragma unroll
        for (int h = 0; h < 5; h++) {
            float l = as[h] + ad[h];
            l = l > 0.f ? l : 0.2f * l;
            float ex = __expf(fminf(l, 60.f));
            sm[h] += ex;
            if (fits) sExp[wv][idx * 5 + h] = ex;
            else      alphap[(size_t)j * 5 + h] = ex;
        }
    }
#pragma unroll
    for (int off = 32; off >= 1; off >>= 1)
#pragma unroll
        for (int h = 0; h < 5; h++) sm[h] += __shfl_xor(sm[h], off);
    float inv[5];
#pragma unroll
    for (int h = 0; h < 5; h++) inv[h] = 1.f / (sm[h] + 1e-16f);

    int h0 = lane >> 4;            // head of ch pair (2l,2l+1): 0..3
    bool lo16 = lane < 16;         // lanes 0..15 own head-4 pair {128+2l,128+2l+1}
    int c01 = 2 * lane;            // first ch pair
    int c2  = 128 + 2 * lane;      // second ch pair (lo16 only; 128..158)
    float2 A  = make_float2(0.f, 0.f), B2 = make_float2(0.f, 0.f);
    float2 A2 = make_float2(0.f, 0.f), B22 = make_float2(0.f, 0.f);

    if (fits) {
        // ---- scatter normalized alpha (lane-parallel) ----
        if (lane < deg) {
            int2 p = sPair[wv][lane];
            float* ao = &alpha_out[(size_t)p.x * 5];
#pragma unroll
            for (int h = 0; h < 5; h++) ao[h] = sExp[wv][lane * 5 + h] * inv[h];
        }
        // ---- aggregation: serial over edges, ch pairs across lanes ----
        int idx = 0;
        for (; idx + 1 < deg; idx += 2) {
            int sA = sPair[wv][idx].y, sB = sPair[wv][idx + 1].y;
            float wA = sExp[wv][idx * 5 + h0] * inv[h0];
            float wB = sExp[wv][(idx + 1) * 5 + h0] * inv[h0];
            const unsigned short* rA = (const unsigned short*)&hmat[(size_t)sA * HID_];
            const unsigned short* rB = (const unsigned short*)&hmat[(size_t)sB * HID_];
            float2 fA = bf2f2(*reinterpret_cast<const uint32_t*>(&rA[c01]));
            float2 fB = bf2f2(*reinterpret_cast<const uint32_t*>(&rB[c01]));
            A.x += wA * fA.x; A.y += wA * fA.y;
            B2.x += wB * fB.x; B2.y += wB * fB.y;
            if (lo16) {
                float wA4 = sExp[wv][idx * 5 + 4] * inv[4];
                float wB4 = sExp[wv][(idx + 1) * 5 + 4] * inv[4];
                float2 gA = bf2f2(*reinterpret_cast<const uint32_t*>(&rA[c2]));
                float2 gB = bf2f2(*reinterpret_cast<const uint32_t*>(&rB[c2]));
                A2.x += wA4 * gA.x; A2.y += wA4 * gA.y;
                B22.x += wB4 * gB.x; B22.y += wB4 * gB.y;
            }
        }
        if (idx < deg) {
            int sA = sPair[wv][idx].y;
            float wA = sExp[wv][idx * 5 + h0] * inv[h0];
            const unsigned short* rA = (const unsigned short*)&hmat[(size_t)sA * HID_];
            float2 fA = bf2f2(*reinterpret_cast<const uint32_t*>(&rA[c01]));
            A.x += wA * fA.x; A.y += wA * fA.y;
            if (lo16) {
                float wA4 = sExp[wv][idx * 5 + 4] * inv[4];
                float2 gA = bf2f2(*reinterpret_cast<const uint32_t*>(&rA[c2]));
                A2.x += wA4 * gA.x; A2.y += wA4 * gA.y;
            }
        }
    } else {
        // ---- overflow path (deg > 64): alpha staged in global scratch ----
        for (int j = start + lane; j < end; j += 64) {
            int2 p = epair[j];
            float* ao = &alpha_out[(size_t)p.x * 5];
#pragma unroll
            for (int h = 0; h < 5; h++) ao[h] = alphap[(size_t)j * 5 + h] * inv[h];
        }
        for (int j = start; j < end; j++) {
            int2 p = epair[j];
            const float* ap = &alphap[(size_t)j * 5];
            float wA = ap[h0] * inv[h0];
            const unsigned short* rA = (const unsigned short*)&hmat[(size_t)p.y * HID_];
            float2 fA = bf2f2(*reinterpret_cast<const uint32_t*>(&rA[c01]));
            A.x += wA * fA.x; A.y += wA * fA.y;
            if (lo16) {
                float wA4 = ap[4] * inv[4];
                float2 gA = bf2f2(*reinterpret_cast<const uint32_t*>(&rA[c2]));
                A2.x += wA4 * gA.x; A2.y += wA4 * gA.y;
            }
        }
    }
    A.x += B2.x; A.y += B2.y; A2.x += B22.x; A2.y += B22.y;

    // ---- bias + leaky(0.01) + LayerNorm ----
    float2 bb = *reinterpret_cast<const float2*>(&bias[c01]);
    float v0 = A.x + bb.x;  v0 = v0 > 0.f ? v0 : 0.01f * v0;
    float v1 = A.y + bb.y;  v1 = v1 > 0.f ? v1 : 0.01f * v1;
    float v2 = 0.f, v3 = 0.f;
    if (lo16) {
        float2 b2 = *reinterpret_cast<const float2*>(&bias[c2]);
        v2 = A2.x + b2.x; v2 = v2 > 0.f ? v2 : 0.01f * v2;
        v3 = A2.y + b2.y; v3 = v3 > 0.f ? v3 : 0.01f * v3;
    }
    float s  = v0 + v1 + v2 + v3;
    float sq = v0 * v0 + v1 * v1 + v2 * v2 + v3 * v3;
#pragma unroll
    for (int off = 32; off >= 1; off >>= 1) {
        s  += __shfl_xor(s, off);
        sq += __shfl_xor(sq, off);
    }
    float m = s * (1.f / 160.f);
    float r = rsqrtf(sq * (1.f / 160.f) - m * m + 1e-5f);
    size_t ob = (size_t)node * HID_;
    {
        float2 sc = *reinterpret_cast<const float2*>(&lns[c01]);
        float2 bi = *reinterpret_cast<const float2*>(&lnb[c01]);
        uint32_t pk = (uint32_t)f2bf((v0 - m) * r * sc.x + bi.x)
                    | ((uint32_t)f2bf((v1 - m) * r * sc.y + bi.y) << 16);
        *reinterpret_cast<uint32_t*>(&outb[ob + c01]) = pk;
    }
    if (lo16) {
        float2 sc = *reinterpret_cast<const float2*>(&lns[c2]);
        float2 bi = *reinterpret_cast<const float2*>(&lnb[c2]);
        uint32_t pk = (uint32_t)f2bf((v2 - m) * r * sc.x + bi.x)
                    | ((uint32_t)f2bf((v3 - m) * r * sc.y + bi.y) << 16);
        *reinterpret_cast<uint32_t*>(&outb[ob + c2]) = pk;
    }
}

// ---------------- readout MLP (single block) ----------------
__global__ __launch_bounds__(256) void k_mlp(const float* __restrict__ pooled, const int* __restrict__ batch,
                                             const float* __restrict__ W1, const float* __restrict__ b1,
                                             const float* __restrict__ lns, const float* __restrict__ lnb,
                                             const float* __restrict__ W2, const float* __restrict__ b2,
                                             float* __restrict__ rec) {
    __shared__ float P[GG][HID_];
    __shared__ float Z[GG][HID_];
    __shared__ float mu[GG], rr[GG], ic[GG];
    int t = threadIdx.x;
    if (t < GG) {
        int lo = lbound_i(batch, NN, t), hi = lbound_i(batch, NN, t + 1);
        ic[t] = 1.f / fmaxf((float)(hi - lo), 1.f);
    }
    __syncthreads();
    for (int i = t; i < GG * HID_; i += 256) P[i / HID_][i % HID_] = pooled[i] * ic[i / HID_];
    __syncthreads();
    for (int i = t; i < GG * HID_; i += 256) {
        int g = i / HID_, j = i % HID_;
        float acc = b1[j];
        for (int k = 0; k < HID_; k++) acc += P[g][k] * W1[k * HID_ + j];
        Z[g][j] = acc;
    }
    __syncthreads();
    if (t < GG) {
        float s = 0.f, sq = 0.f;
        for (int k = 0; k < HID_; k++) { float z = Z[t][k]; s += z; sq += z * z; }
        float m = s / (float)HID_;
        mu[t] = m;
        rr[t] = rsqrtf(sq / (float)HID_ - m * m + 1e-5f);
    }
    __syncthreads();
    for (int i = t; i < GG * HID_; i += 256) {
        int g = i / HID_, j = i % HID_;
        float z = (Z[g][j] - mu[g]) * rr[g] * lns[j] + lnb[j];
        Z[g][j] = fmaxf(z, 0.f);
    }
    __syncthreads();
    for (int i = t; i < GG * NC_; i += 256) {
        int g = i / NC_, j = i % NC_;
        float acc = b2[j];
        for (int k = 0; k < HID_; k++) acc += Z[g][k] * W2[k * NC_ + j];
        rec[g * NC_ + j] = acc;
    }
}

extern "C" void kernel_launch(void* const* d_in, const int* in_sizes, int n_in,
                              void* d_out, int out_size, void* d_ws, size_t ws_size,
                              hipStream_t stream) {
    const float* x    = (const float*)d_in[0];
    const int*   ei   = (const int*)d_in[1];
    const int*   batch= (const int*)d_in[2];
    const float* W1   = (const float*)d_in[3];
    const float* as1  = (const float*)d_in[4];
    const float* ad1  = (const float*)d_in[5];
    const float* b1   = (const float*)d_in[6];
    const float* ln1s = (const float*)d_in[7];
    const float* ln1b = (const float*)d_in[8];
    const float* W2   = (const float*)d_in[9];
    const float* as2  = (const float*)d_in[10];
    const float* ad2  = (const float*)d_in[11];
    const float* b2   = (const float*)d_in[12];
    const float* ln2s = (const float*)d_in[13];
    const float* ln2b = (const float*)d_in[14];
    const float* Wm   = (const float*)d_in[15];
    const float* bm   = (const float*)d_in[16];
    const float* Wm1  = (const float*)d_in[17];
    const float* bm1  = (const float*)d_in[18];
    const float* ln3s = (const float*)d_in[19];
    const float* ln3b = (const float*)d_in[20];
    const float* Wm2  = (const float*)d_in[21];
    const float* bm2  = (const float*)d_in[22];

    float* out    = (float*)d_out;
    float* xo     = out;                              // N*160
    float* rec    = out + (size_t)NN * HID_;          // 8*20
    float* alpha1 = rec + GG * NC_;                   // ET*5
    float* alpha2 = alpha1 + (size_t)ET_ * 5;         // ET*5

    char* w = (char*)d_ws;
    auto carve = [&](size_t bytes) { char* p = w; w += (bytes + 255) & ~(size_t)255; return p; };
    int*   deg    = (int*)carve((size_t)NN * 4);
    int*   rowptr = (int*)carve((size_t)(NN + 1) * 4);
    int*   cursor = (int*)carve((size_t)NN * 4);
    int2*  epair  = (int2*)carve((size_t)ET_ * 8);
    int*   bsum   = (int*)carve(64 * 4);
    __hip_bfloat16* hbuf  = (__hip_bfloat16*)carve((size_t)NN * HID_ * 2);
    __hip_bfloat16* xbufb = (__hip_bfloat16*)carve((size_t)NN * HID_ * 2);
    float* alphap = (float*)carve((size_t)ET_ * 5 * 4);
    float* als    = (float*)carve((size_t)NN * 5 * 4);
    float* ald    = (float*)carve((size_t)NN * 5 * 4);
    float* pooled = (float*)carve((size_t)GG * HID_ * 4);
    unsigned short* Wt1 = (unsigned short*)carve((size_t)HID_ * 512 * 2);
    unsigned short* Wt2 = (unsigned short*)carve((size_t)HID_ * HID_ * 2);
    unsigned short* Wmt = (unsigned short*)carve((size_t)HID_ * HID_ * 2);

    // ---- CSR by destination (rebuilt every call; ws is re-poisoned) ----
    hipMemsetAsync(deg, 0, (size_t)NN * 4, stream);
    k_hist<<<(ET_ + 255) / 256, 256, 0, stream>>>(ei, deg);
    int nb = (NN + 1023) / 1024;
    k_scan1<<<nb, 256, 0, stream>>>(deg, rowptr, bsum);
    k_scan2<<<1, 64, 0, stream>>>(bsum, nb);
    k_scan3<<<(NN + 1 + 255) / 256, 256, 0, stream>>>(rowptr, bsum, cursor);
    k_scatter<<<(ET_ + 255) / 256, 256, 0, stream>>>(ei, cursor, epair);

    // ---- weight prep (one launch; also zeroes pooled for gemm3) ----
    const int PREP = HID_ * 512 + 2 * HID_ * HID_;
    k_prep_all<<<(PREP + 255) / 256, 256, 0, stream>>>(W1, Wt1, W2, Wt2, Wm, Wmt, pooled);

    const int NWB = (NN + 3) / 4;         // wave-per-node blocks (4 waves/block)
    const int GB  = (NN + 63) / 64;       // register-GEMM blocks (64 rows each)

    // ---- layer 1 ----
    k_gemm_f32<<<GB, 256, 0, stream>>>(x, Wt1, nullptr, hbuf, NN, FIN, 512, nullptr, 0,
                                       as1, ad1, als, ald, nullptr, nullptr);
    k_att_agg<<<NWB, 256, 0, stream>>>(rowptr, epair, als, ald, hbuf, alphap, alpha1,
                                       b1, ln1s, ln1b, xbufb);

    // ---- layer 2 ----
    k_gemm_bf16<<<GB, 256, 0, stream>>>(xbufb, Wt2, nullptr, hbuf, NN, HID_, HID_, nullptr, 0,
                                        as2, ad2, als, ald, nullptr, nullptr);
    k_att_agg<<<NWB, 256, 0, stream>>>(rowptr, epair, als, ald, hbuf, alphap, alpha2,
                                       b2, ln2s, ln2b, xbufb);

    // ---- readout: GEMM + fused mean-pool partials ----
    k_gemm_bf16<<<GB, 256, 0, stream>>>(xbufb, Wmt, xo, nullptr, NN, HID_, HID_, bm, 1,
                                        nullptr, nullptr, nullptr, nullptr, batch, pooled);
    k_mlp<<<1, 256, 0, stream>>>(pooled, batch, Wm1, bm1, ln3s, ln3b, Wm2, bm2, rec);
}

// Round 3
// 647.409 us; speedup vs baseline: 1.1076x; 1.1076x over previous
//
#include <hip/hip_runtime.h>
#include <hip/hip_bf16.h>
#include <cstdint>
#include <cstddef>

#define NN   50000
#define EE   800000
#define ET_  (EE + NN)      // 850000 edges incl. self-loops
#define FIN  500
#define HID_ 160
#define NC_  20
#define GG   8
#define GB1  ((NN + 63) / 64)   // 782 GEMM blocks (64 rows each)
#define NK1  16                 // layer-1 k-steps (K=500 padded to 512)
#define NK2  5                  // K=160 k-steps

typedef __attribute__((ext_vector_type(8))) short ab8;   // 8 bf16 (4 VGPRs)
typedef __attribute__((ext_vector_type(4))) float f4;    // MFMA accumulator

static __device__ __forceinline__ unsigned short f2bf(float v) {
    union { float f; uint32_t u; } c; c.f = v;
    uint32_t r = c.u + 0x7FFFu + ((c.u >> 16) & 1u);  // RNE
    return (unsigned short)(r >> 16);
}

static __device__ __forceinline__ float2 bf2f2(uint32_t u) {
    // u holds bf16 pair (lo = even ch, hi = odd ch)
    union { uint32_t u; float f; } a, b;
    a.u = u << 16;
    b.u = u & 0xffff0000u;
    return make_float2(a.f, b.f);
}

static __device__ __forceinline__ int lbound_i(const int* arr, int n, int val) {
    int lo = 0, hi = n;
    while (lo < hi) { int mid = (lo + hi) >> 1; if (arr[mid] < val) lo = mid + 1; else hi = mid; }
    return lo;
}

// ---------------- CSR build ----------------
__global__ __launch_bounds__(256) void k_hist(const int* __restrict__ ei, int* __restrict__ deg) {
    int e = blockIdx.x * 256 + threadIdx.x;
    if (e >= ET_) return;
    int d = (e < EE) ? ei[EE + e] : (e - EE);
    atomicAdd(&deg[d], 1);
}

__global__ __launch_bounds__(256) void k_scan1(const int* __restrict__ deg, int* __restrict__ rowptr,
                                               int* __restrict__ bsum) {
    __shared__ int s[256];
    int t = threadIdx.x;
    int base = blockIdx.x * 1024 + t * 4;
    int v0 = (base + 0 < NN) ? deg[base + 0] : 0;
    int v1 = (base + 1 < NN) ? deg[base + 1] : 0;
    int v2 = (base + 2 < NN) ? deg[base + 2] : 0;
    int v3 = (base + 3 < NN) ? deg[base + 3] : 0;
    int tot = v0 + v1 + v2 + v3;
    s[t] = tot;
    __syncthreads();
    for (int off = 1; off < 256; off <<= 1) {
        int y = (t >= off) ? s[t - off] : 0;
        __syncthreads();
        s[t] += y;
        __syncthreads();
    }
    int excl = s[t] - tot;
    if (t == 255) bsum[blockIdx.x] = s[255];
    if (base + 0 < NN) rowptr[base + 0] = excl;  excl += v0;
    if (base + 1 < NN) rowptr[base + 1] = excl;  excl += v1;
    if (base + 2 < NN) rowptr[base + 2] = excl;  excl += v2;
    if (base + 3 < NN) rowptr[base + 3] = excl;
}

__global__ void k_scan2(int* __restrict__ bsum, int nb) {
    int t = threadIdx.x; // single wave of 64; nb <= 64
    int v = (t < nb) ? bsum[t] : 0;
    int orig = v;
    for (int off = 1; off < 64; off <<= 1) {
        int y = __shfl_up(v, off);
        if (t >= off) v += y;
    }
    if (t < nb) bsum[t] = v - orig; // exclusive prefix
}

__global__ __launch_bounds__(256) void k_scan3(int* __restrict__ rowptr, const int* __restrict__ bsum,
                                               int* __restrict__ cursor) {
    int i = blockIdx.x * 256 + threadIdx.x;
    if (i < NN) {
        int r = rowptr[i] + bsum[i >> 10];
        rowptr[i] = r;
        cursor[i] = r;
    }
    if (i == NN) rowptr[NN] = ET_;
}

__global__ __launch_bounds__(256) void k_scatter(const int* __restrict__ ei, int* __restrict__ cursor,
                                                 int2* __restrict__ epair) {
    int e = blockIdx.x * 256 + threadIdx.x;
    if (e >= ET_) return;
    int s, d;
    if (e < EE) { s = ei[e]; d = ei[EE + e]; } else { s = e - EE; d = e - EE; }
    int slot = atomicAdd(&cursor[d], 1);
    epair[slot] = make_int2(e, s);
}

// ---------------- weight prep: fragment-packed B for all three GEMMs ----------------
// Bpk chunk (s,t,l): the 16B ab8 that lane l feeds MFMA t at k-step s.
// chunk value = W^T[n = t*16 + (l&15)][k0 = s*32 + (l>>4)*8 .. +8], zero-padded past K.
// Makes every B-fragment load in the GEMM a fully-coalesced 1KB wave burst.
__global__ __launch_bounds__(256) void k_prep_all(const float* __restrict__ W1, ab8* __restrict__ B1,
                                                  const float* __restrict__ W2, ab8* __restrict__ B2,
                                                  const float* __restrict__ Wm, ab8* __restrict__ Bm,
                                                  float* __restrict__ pooled) {
    int idx = blockIdx.x * 256 + threadIdx.x;
    if (idx < GG * HID_) pooled[idx] = 0.f;
    const int C1 = NK1 * 10 * 64;      // 10240 chunks
    const int C2 = NK2 * 10 * 64;      // 3200 chunks
    const float* W; ab8* Bo; int K, cidx;
    if (idx < C1)                { W = W1; Bo = B1; K = FIN;  cidx = idx; }
    else if (idx < C1 + C2)      { W = W2; Bo = B2; K = HID_; cidx = idx - C1; }
    else if (idx < C1 + 2 * C2)  { W = Wm; Bo = Bm; K = HID_; cidx = idx - C1 - C2; }
    else return;
    int s = cidx / 640, r = cidx % 640;
    int t = r >> 6, l = r & 63;
    int fr = l & 15, q = l >> 4;
    int n  = t * 16 + fr;
    int k0 = s * 32 + q * 8;
    unsigned short pk[8];
#pragma unroll
    for (int j = 0; j < 8; j++) {
        int k = k0 + j;
        pk[j] = (k < K) ? f2bf(W[(size_t)k * HID_ + n]) : (unsigned short)0;
    }
    Bo[cidx] = *reinterpret_cast<ab8*>(pk);
}

// ---------------- x fp32 -> fragment-packed bf16 A for layer 1 ----------------
// Apk chunk ((blk*NK1 + s)*256 + tid): the ab8 that thread tid of GEMM block blk
// feeds its MFMA at k-step s. Output writes fully coalesced; removes all f2bf
// VALU work and the 16-row scatter from the layer-1 GEMM hot loop.
// NOTE: Apk lives in the first 51.25MB of d_out (dead until later kernels) —
// keeping d_ws usage at the ~58MB level that is known to fit.
__global__ __launch_bounds__(256) void k_conv_x(const float* __restrict__ x, ab8* __restrict__ Apk) {
    int idx = blockIdx.x * 256 + threadIdx.x;   // grid is exactly GB1*NK1*256 chunks
    int tid = idx & 255;
    int s   = (idx >> 8) & (NK1 - 1);
    int blk = idx >> 12;                         // NK1*256 = 4096
    int l = tid & 63, w = tid >> 6;
    int fr = l & 15, q = l >> 4;
    int row = blk * 64 + w * 16 + fr;
    int k0 = s * 32 + q * 8;
    unsigned short pk[8] = {0, 0, 0, 0, 0, 0, 0, 0};
    if (row < NN) {
        const float* xr = &x[(size_t)row * FIN];
        if (k0 + 8 <= FIN) {
            const float4* s4 = reinterpret_cast<const float4*>(&xr[k0]);
            float4 u = s4[0], v = s4[1];
            pk[0] = f2bf(u.x); pk[1] = f2bf(u.y); pk[2] = f2bf(u.z); pk[3] = f2bf(u.w);
            pk[4] = f2bf(v.x); pk[5] = f2bf(v.y); pk[6] = f2bf(v.z); pk[7] = f2bf(v.w);
        } else {
#pragma unroll
            for (int j = 0; j < 8; j++)
                if (k0 + j < FIN) pk[j] = f2bf(xr[k0 + j]);
        }
    }
    Apk[idx] = *reinterpret_cast<ab8*>(pk);
}

// ---------------- register-resident MFMA GEMM: C[M,160] = A[M,K] @ W[K,160] ----------------
// NO LDS, NO barriers, NO scattered loads: B is fragment-packed (each load = 1KB
// coalesced wave burst, double-buffered in regs); layer-1 A is fragment-packed
// (4KB contiguous per block-step, depth-2 prefetch). Layers 2/3 read row-major
// bf16 A (16MB total, K=160).
// Fused epilogues preserved:
//  - asrc/adst -> als/ald: per-row per-head attention dots (GAT layers)
//  - batch+pooled: global mean-pool partial sums (readout GEMM)
template<int PKA>
static __device__ __forceinline__ void gemm_body(const void* __restrict__ Av,
                                                 const ab8* __restrict__ Bpk, int nk,
                                                 float* __restrict__ C, __hip_bfloat16* __restrict__ Cb,
                                                 int M, int K,
                                                 const float* __restrict__ bias, int act,
                                                 const float* __restrict__ asrc, const float* __restrict__ adst,
                                                 float* __restrict__ als_o, float* __restrict__ ald_o,
                                                 const int* __restrict__ batch_p, float* __restrict__ pooled) {
    int tid  = threadIdx.x;
    int lane = tid & 63;
    int w    = tid >> 6;
    int fr   = lane & 15;        // fragment row/col index
    int q    = lane >> 4;        // quad: k-subtile for inputs, row-subtile for output
    int row0 = blockIdx.x * 64;
    int arow = row0 + w * 16 + fr;   // row whose A-fragment this lane supplies
    bool rv  = arow < M;

    f4 acc[10];
#pragma unroll
    for (int t = 0; t < 10; t++) acc[t] = (f4)0.f;

    const ab8* bb  = Bpk + lane;
    const ab8* apk = reinterpret_cast<const ab8*>(Av) + (size_t)blockIdx.x * nk * 256 + tid;
    const unsigned short* Arow = (const unsigned short*)Av;

    auto loadA = [&](int s) -> ab8 {
        if (PKA) return apk[s * 256];
        ab8 a = (ab8)0;
        if (rv) a = *reinterpret_cast<const ab8*>(&Arow[(size_t)arow * K + s * 32 + q * 8]);
        return a;
    };

    ab8 bcur[10], bnx[10];
#pragma unroll
    for (int t = 0; t < 10; t++) bcur[t] = bb[t * 64];
    ab8 a0 = loadA(0);
    ab8 a1 = loadA(1);                // nk >= 5 always
    for (int s = 0; s < nk; s++) {
        if (s + 1 < nk) {
#pragma unroll
            for (int t = 0; t < 10; t++) bnx[t] = bb[((s + 1) * 10 + t) * 64];
        }
        ab8 a2 = (ab8)0;
        if (s + 2 < nk) a2 = loadA(s + 2);
#pragma unroll
        for (int t = 0; t < 10; t++)
            acc[t] = __builtin_amdgcn_mfma_f32_16x16x32_bf16(a0, bcur[t], acc[t], 0, 0, 0);
        a0 = a1; a1 = a2;
#pragma unroll
        for (int t = 0; t < 10; t++) bcur[t] = bnx[t];
    }

    // ---- fused per-node attention dots: als/ald (GAT layers) ----
    if (als_o) {
        float av_s[10], av_d[10];
#pragma unroll
        for (int t = 0; t < 10; t++) { av_s[t] = asrc[t * 16 + fr]; av_d[t] = adst[t * 16 + fr]; }
#pragma unroll
        for (int i = 0; i < 4; i++) {
            int r = row0 + w * 16 + q * 4 + i;
            float ps[5], pd[5];
#pragma unroll
            for (int h = 0; h < 5; h++) {
                ps[h] = acc[2 * h][i] * av_s[2 * h] + acc[2 * h + 1][i] * av_s[2 * h + 1];
                pd[h] = acc[2 * h][i] * av_d[2 * h] + acc[2 * h + 1][i] * av_d[2 * h + 1];
            }
#pragma unroll
            for (int off = 8; off >= 1; off >>= 1)
#pragma unroll
                for (int h = 0; h < 5; h++) {
                    ps[h] += __shfl_xor(ps[h], off);
                    pd[h] += __shfl_xor(pd[h], off);
                }
            if (fr == 0 && r < M) {
#pragma unroll
                for (int h = 0; h < 5; h++) {
                    als_o[(size_t)r * 5 + h] = ps[h];
                    ald_o[(size_t)r * 5 + h] = pd[h];
                }
            }
        }
    }

    // ---- pool setup (readout GEMM): block-uniform-graph fast path ----
    int gu = -2;
    if (pooled) {
        int rhi = row0 + 63; if (rhi >= M) rhi = M - 1;
        int gl = batch_p[row0], gh = batch_p[rhi];
        gu = (gl == gh) ? gl : -1;
    }
    float psum[10];
#pragma unroll
    for (int t = 0; t < 10; t++) psum[t] = 0.f;

    // ---- epilogue: C/D layout col=lane&15, row=(lane>>4)*4+reg ----
    int rbase = row0 + w * 16 + q * 4;
#pragma unroll
    for (int t = 0; t < 10; t++) {
        int col = t * 16 + fr;
        float bv = bias ? bias[col] : 0.f;
#pragma unroll
        for (int i = 0; i < 4; i++) {
            int r = rbase + i;
            float v = acc[t][i] + bv;
            if (act) v = v > 0.f ? v : 0.01f * v;
            if (r < M) {
                if (C)  C[(size_t)r * HID_ + col] = v;
                if (Cb) *reinterpret_cast<unsigned short*>(&Cb[(size_t)r * HID_ + col]) = f2bf(v);
                if (gu >= 0) psum[t] += v;
                else if (gu == -1) atomicAdd(&pooled[batch_p[r] * HID_ + col], v);
            }
        }
    }
    if (gu >= 0) {
#pragma unroll
        for (int t = 0; t < 10; t++) {
            psum[t] += __shfl_xor(psum[t], 16);
            psum[t] += __shfl_xor(psum[t], 32);
        }
        if (q == 0) {
#pragma unroll
            for (int t = 0; t < 10; t++)
                atomicAdd(&pooled[gu * HID_ + t * 16 + fr], psum[t]);
        }
    }
}

__global__ __launch_bounds__(256) void k_gemm_pk(const void* __restrict__ Av,
                                                 const ab8* __restrict__ Bpk, int nk,
                                                 float* __restrict__ C, __hip_bfloat16* __restrict__ Cb,
                                                 int M, int K,
                                                 const float* __restrict__ bias, int act,
                                                 const float* __restrict__ asrc, const float* __restrict__ adst,
                                                 float* __restrict__ als_o, float* __restrict__ ald_o,
                                                 const int* __restrict__ batch_p, float* __restrict__ pooled) {
    gemm_body<1>(Av, Bpk, nk, C, Cb, M, K, bias, act, asrc, adst, als_o, ald_o, batch_p, pooled);
}

__global__ __launch_bounds__(256) void k_gemm_rm(const void* __restrict__ Av,
                                                 const ab8* __restrict__ Bpk, int nk,
                                                 float* __restrict__ C, __hip_bfloat16* __restrict__ Cb,
                                                 int M, int K,
                                                 const float* __restrict__ bias, int act,
                                                 const float* __restrict__ asrc, const float* __restrict__ adst,
                                                 float* __restrict__ als_o, float* __restrict__ ald_o,
                                                 const int* __restrict__ batch_p, float* __restrict__ pooled) {
    gemm_body<0>(Av, Bpk, nk, C, Cb, M, K, bias, act, asrc, adst, als_o, ald_o, batch_p, pooled);
}

// ---------- fused edge softmax + aggregation + bias + leaky + LayerNorm ----------
// One wave per destination node. Channel map: lane l owns ch {2l,2l+1}; lanes 0..15
// additionally own {128+2l,128+2l+1} (head 4). 4B ushort2 gathers (2 loads/edge).
__global__ __launch_bounds__(256) void k_att_agg(const int* __restrict__ rowptr,
                                                 const int2* __restrict__ epair,
                                                 const float* __restrict__ als, const float* __restrict__ ald,
                                                 const __hip_bfloat16* __restrict__ hmat,
                                                 float* __restrict__ alphap,      // [ET_*5] overflow scratch
                                                 float* __restrict__ alpha_out,   // [ET_*5] edge-id order
                                                 const float* __restrict__ bias,
                                                 const float* __restrict__ lns, const float* __restrict__ lnb,
                                                 __hip_bfloat16* __restrict__ outb) {
    __shared__ float sExp[4][64 * 5];
    __shared__ int2  sPair[4][64];
    int wv   = threadIdx.x >> 6;
    int lane = threadIdx.x & 63;
    int node = blockIdx.x * 4 + wv;
    if (node >= NN) return;
    int start = rowptr[node], end = rowptr[node + 1];
    int deg = end - start;
    bool fits = (deg <= 64);
    float ad[5];
#pragma unroll
    for (int h = 0; h < 5; h++) ad[h] = ald[node * 5 + h];

    // ---- pass 1: exp(leaky(logit)), lane-parallel over edges ----
    float sm[5] = {0.f, 0.f, 0.f, 0.f, 0.f};
    for (int j = start + lane; j < end; j += 64) {
        int2 p = epair[j];
        const float* as = &als[(size_t)p.y * 5];
        int idx = j - start;
        if (fits) sPair[wv][idx] = p;
#pragma unroll
        for (int h = 0; h < 5; h++) {
            float l = as[h] + ad[h];
            l = l > 0.f ? l : 0.2f * l;
            float ex = __expf(fminf(l, 60.f));
            sm[h] += ex;
            if (fits) sExp[wv][idx * 5 + h] = ex;
            else      alphap[(size_t)j * 5 + h] = ex;
        }
    }
#pragma unroll
    for (int off = 32; off >= 1; off >>= 1)
#pragma unroll
        for (int h = 0; h < 5; h++) sm[h] += __shfl_xor(sm[h], off);
    float inv[5];
#pragma unroll
    for (int h = 0; h < 5; h++) inv[h] = 1.f / (sm[h] + 1e-16f);

    int h0 = lane >> 4;            // head of ch pair (2l,2l+1): 0..3
    bool lo16 = lane < 16;         // lanes 0..15 own head-4 pair {128+2l,128+2l+1}
    int c01 = 2 * lane;            // first ch pair
    int c2  = 128 + 2 * lane;      // second ch pair (lo16 only; 128..158)
    float2 A  = make_float2(0.f, 0.f), B2 = make_float2(0.f, 0.f);
    float2 A2 = make_float2(0.f, 0.f), B22 = make_float2(0.f, 0.f);

    if (fits) {
        // ---- scatter normalized alpha (lane-parallel) ----
        if (lane < deg) {
            int2 p = sPair[wv][lane];
            float* ao = &alpha_out[(size_t)p.x * 5];
#pragma unroll
            for (int h = 0; h < 5; h++) ao[h] = sExp[wv][lane * 5 + h] * inv[h];
        }
        // ---- aggregation: serial over edges, ch pairs across lanes ----
        int idx = 0;
        for (; idx + 1 < deg; idx += 2) {
            int sA = sPair[wv][idx].y, sB = sPair[wv][idx + 1].y;
            float wA = sExp[wv][idx * 5 + h0] * inv[h0];
            float wB = sExp[wv][(idx + 1) * 5 + h0] * inv[h0];
            const unsigned short* rA = (const unsigned short*)&hmat[(size_t)sA * HID_];
            const unsigned short* rB = (const unsigned short*)&hmat[(size_t)sB * HID_];
            float2 fA = bf2f2(*reinterpret_cast<const uint32_t*>(&rA[c01]));
            float2 fB = bf2f2(*reinterpret_cast<const uint32_t*>(&rB[c01]));
            A.x += wA * fA.x; A.y += wA * fA.y;
            B2.x += wB * fB.x; B2.y += wB * fB.y;
            if (lo16) {
                float wA4 = sExp[wv][idx * 5 + 4] * inv[4];
                float wB4 = sExp[wv][(idx + 1) * 5 + 4] * inv[4];
                float2 gA = bf2f2(*reinterpret_cast<const uint32_t*>(&rA[c2]));
                float2 gB = bf2f2(*reinterpret_cast<const uint32_t*>(&rB[c2]));
                A2.x += wA4 * gA.x; A2.y += wA4 * gA.y;
                B22.x += wB4 * gB.x; B22.y += wB4 * gB.y;
            }
        }
        if (idx < deg) {
            int sA = sPair[wv][idx].y;
            float wA = sExp[wv][idx * 5 + h0] * inv[h0];
            const unsigned short* rA = (const unsigned short*)&hmat[(size_t)sA * HID_];
            float2 fA = bf2f2(*reinterpret_cast<const uint32_t*>(&rA[c01]));
            A.x += wA * fA.x; A.y += wA * fA.y;
            if (lo16) {
                float wA4 = sExp[wv][idx * 5 + 4] * inv[4];
                float2 gA = bf2f2(*reinterpret_cast<const uint32_t*>(&rA[c2]));
                A2.x += wA4 * gA.x; A2.y += wA4 * gA.y;
            }
        }
    } else {
        // ---- overflow path (deg > 64): alpha staged in global scratch ----
        for (int j = start + lane; j < end; j += 64) {
            int2 p = epair[j];
            float* ao = &alpha_out[(size_t)p.x * 5];
#pragma unroll
            for (int h = 0; h < 5; h++) ao[h] = alphap[(size_t)j * 5 + h] * inv[h];
        }
        for (int j = start; j < end; j++) {
            int2 p = epair[j];
            const float* ap = &alphap[(size_t)j * 5];
            float wA = ap[h0] * inv[h0];
            const unsigned short* rA = (const unsigned short*)&hmat[(size_t)p.y * HID_];
            float2 fA = bf2f2(*reinterpret_cast<const uint32_t*>(&rA[c01]));
            A.x += wA * fA.x; A.y += wA * fA.y;
            if (lo16) {
                float wA4 = ap[4] * inv[4];
                float2 gA = bf2f2(*reinterpret_cast<const uint32_t*>(&rA[c2]));
                A2.x += wA4 * gA.x; A2.y += wA4 * gA.y;
            }
        }
    }
    A.x += B2.x; A.y += B2.y; A2.x += B22.x; A2.y += B22.y;

    // ---- bias + leaky(0.01) + LayerNorm ----
    float2 bb = *reinterpret_cast<const float2*>(&bias[c01]);
    float v0 = A.x + bb.x;  v0 = v0 > 0.f ? v0 : 0.01f * v0;
    float v1 = A.y + bb.y;  v1 = v1 > 0.f ? v1 : 0.01f * v1;
    float v2 = 0.f, v3 = 0.f;
    if (lo16) {
        float2 b2 = *reinterpret_cast<const float2*>(&bias[c2]);
        v2 = A2.x + b2.x; v2 = v2 > 0.f ? v2 : 0.01f * v2;
        v3 = A2.y + b2.y; v3 = v3 > 0.f ? v3 : 0.01f * v3;
    }
    float s  = v0 + v1 + v2 + v3;
    float sq = v0 * v0 + v1 * v1 + v2 * v2 + v3 * v3;
#pragma unroll
    for (int off = 32; off >= 1; off >>= 1) {
        s  += __shfl_xor(s, off);
        sq += __shfl_xor(sq, off);
    }
    float m = s * (1.f / 160.f);
    float r = rsqrtf(sq * (1.f / 160.f) - m * m + 1e-5f);
    size_t ob = (size_t)node * HID_;
    {
        float2 sc = *reinterpret_cast<const float2*>(&lns[c01]);
        float2 bi = *reinterpret_cast<const float2*>(&lnb[c01]);
        uint32_t pk = (uint32_t)f2bf((v0 - m) * r * sc.x + bi.x)
                    | ((uint32_t)f2bf((v1 - m) * r * sc.y + bi.y) << 16);
        *reinterpret_cast<uint32_t*>(&outb[ob + c01]) = pk;
    }
    if (lo16) {
        float2 sc = *reinterpret_cast<const float2*>(&lns[c2]);
        float2 bi = *reinterpret_cast<const float2*>(&lnb[c2]);
        uint32_t pk = (uint32_t)f2bf((v2 - m) * r * sc.x + bi.x)
                    | ((uint32_t)f2bf((v3 - m) * r * sc.y + bi.y) << 16);
        *reinterpret_cast<uint32_t*>(&outb[ob + c2]) = pk;
    }
}

// ---------------- readout MLP (single block) ----------------
__global__ __launch_bounds__(256) void k_mlp(const float* __restrict__ pooled, const int* __restrict__ batch,
                                             const float* __restrict__ W1, const float* __restrict__ b1,
                                             const float* __restrict__ lns, const float* __restrict__ lnb,
                                             const float* __restrict__ W2, const float* __restrict__ b2,
                                             float* __restrict__ rec) {
    __shared__ float P[GG][HID_];
    __shared__ float Z[GG][HID_];
    __shared__ float mu[GG], rr[GG], ic[GG];
    int t = threadIdx.x;
    if (t < GG) {
        int lo = lbound_i(batch, NN, t), hi = lbound_i(batch, NN, t + 1);
        ic[t] = 1.f / fmaxf((float)(hi - lo), 1.f);
    }
    __syncthreads();
    for (int i = t; i < GG * HID_; i += 256) P[i / HID_][i % HID_] = pooled[i] * ic[i / HID_];
    __syncthreads();
    for (int i = t; i < GG * HID_; i += 256) {
        int g = i / HID_, j = i % HID_;
        float acc = b1[j];
        for (int k = 0; k < HID_; k++) acc += P[g][k] * W1[k * HID_ + j];
        Z[g][j] = acc;
    }
    __syncthreads();
    if (t < GG) {
        float s = 0.f, sq = 0.f;
        for (int k = 0; k < HID_; k++) { float z = Z[t][k]; s += z; sq += z * z; }
        float m = s / (float)HID_;
        mu[t] = m;
        rr[t] = rsqrtf(sq / (float)HID_ - m * m + 1e-5f);
    }
    __syncthreads();
    for (int i = t; i < GG * HID_; i += 256) {
        int g = i / HID_, j = i % HID_;
        float z = (Z[g][j] - mu[g]) * rr[g] * lns[j] + lnb[j];
        Z[g][j] = fmaxf(z, 0.f);
    }
    __syncthreads();
    for (int i = t; i < GG * NC_; i += 256) {
        int g = i / NC_, j = i % NC_;
        float acc = b2[j];
        for (int k = 0; k < HID_; k++) acc += Z[g][k] * W2[k * NC_ + j];
        rec[g * NC_ + j] = acc;
    }
}

extern "C" void kernel_launch(void* const* d_in, const int* in_sizes, int n_in,
                              void* d_out, int out_size, void* d_ws, size_t ws_size,
                              hipStream_t stream) {
    const float* x    = (const float*)d_in[0];
    const int*   ei   = (const int*)d_in[1];
    const int*   batch= (const int*)d_in[2];
    const float* W1   = (const float*)d_in[3];
    const float* as1  = (const float*)d_in[4];
    const float* ad1  = (const float*)d_in[5];
    const float* b1   = (const float*)d_in[6];
    const float* ln1s = (const float*)d_in[7];
    const float* ln1b = (const float*)d_in[8];
    const float* W2   = (const float*)d_in[9];
    const float* as2  = (const float*)d_in[10];
    const float* ad2  = (const float*)d_in[11];
    const float* b2   = (const float*)d_in[12];
    const float* ln2s = (const float*)d_in[13];
    const float* ln2b = (const float*)d_in[14];
    const float* Wm   = (const float*)d_in[15];
    const float* bm   = (const float*)d_in[16];
    const float* Wm1  = (const float*)d_in[17];
    const float* bm1  = (const float*)d_in[18];
    const float* ln3s = (const float*)d_in[19];
    const float* ln3b = (const float*)d_in[20];
    const float* Wm2  = (const float*)d_in[21];
    const float* bm2  = (const float*)d_in[22];

    float* out    = (float*)d_out;
    float* xo     = out;                              // N*160
    float* rec    = out + (size_t)NN * HID_;          // 8*20
    float* alpha1 = rec + GG * NC_;                   // ET*5
    float* alpha2 = alpha1 + (size_t)ET_ * 5;         // ET*5

    char* w = (char*)d_ws;
    auto carve = [&](size_t bytes) { char* p = w; w += (bytes + 255) & ~(size_t)255; return p; };
    int*   deg    = (int*)carve((size_t)NN * 4);
    int*   rowptr = (int*)carve((size_t)(NN + 1) * 4);
    int*   cursor = (int*)carve((size_t)NN * 4);
    int2*  epair  = (int2*)carve((size_t)ET_ * 8);
    int*   bsum   = (int*)carve(64 * 4);
    __hip_bfloat16* hbuf  = (__hip_bfloat16*)carve((size_t)NN * HID_ * 2);
    __hip_bfloat16* xbufb = (__hip_bfloat16*)carve((size_t)NN * HID_ * 2);
    float* alphap = (float*)carve((size_t)ET_ * 5 * 4);
    float* als    = (float*)carve((size_t)NN * 5 * 4);
    float* ald    = (float*)carve((size_t)NN * 5 * 4);
    float* pooled = (float*)carve((size_t)GG * HID_ * 4);
    ab8*   B1pk   = (ab8*)carve((size_t)NK1 * 10 * 64 * 16);     // 160 KB
    ab8*   B2pk   = (ab8*)carve((size_t)NK2 * 10 * 64 * 16);     // 50 KB
    ab8*   Bmpk   = (ab8*)carve((size_t)NK2 * 10 * 64 * 16);     // 50 KB
    // Apk (51.25MB) lives in d_out: that region (xo + rec + start of alpha1,
    // 66MB total) is dead until k_att_agg/readout, which all run after the
    // layer-1 GEMM finishes reading Apk. Keeps d_ws at the proven ~58MB.
    ab8*   Apk    = (ab8*)d_out;                                 // GB1*NK1*256*16 B

    // ---- CSR by destination (rebuilt every call; ws is re-poisoned) ----
    hipMemsetAsync(deg, 0, (size_t)NN * 4, stream);
    k_hist<<<(ET_ + 255) / 256, 256, 0, stream>>>(ei, deg);
    int nb = (NN + 1023) / 1024;
    k_scan1<<<nb, 256, 0, stream>>>(deg, rowptr, bsum);
    k_scan2<<<1, 64, 0, stream>>>(bsum, nb);
    k_scan3<<<(NN + 1 + 255) / 256, 256, 0, stream>>>(rowptr, bsum, cursor);
    k_scatter<<<(ET_ + 255) / 256, 256, 0, stream>>>(ei, cursor, epair);

    // ---- weight prep (fragment-packed B; also zeroes pooled) + packed-A conversion ----
    const int PREP = NK1 * 10 * 64 + 2 * NK2 * 10 * 64;  // 16640 chunk threads
    k_prep_all<<<(PREP + 255) / 256, 256, 0, stream>>>(W1, B1pk, W2, B2pk, Wm, Bmpk, pooled);
    k_conv_x<<<GB1 * NK1, 256, 0, stream>>>(x, Apk);

    const int NWB = (NN + 3) / 4;         // wave-per-node blocks (4 waves/block)

    // ---- layer 1 ----
    k_gemm_pk<<<GB1, 256, 0, stream>>>(Apk, B1pk, NK1, nullptr, hbuf, NN, FIN, nullptr, 0,
                                       as1, ad1, als, ald, nullptr, nullptr);
    k_att_agg<<<NWB, 256, 0, stream>>>(rowptr, epair, als, ald, hbuf, alphap, alpha1,
                                       b1, ln1s, ln1b, xbufb);

    // ---- layer 2 ----
    k_gemm_rm<<<GB1, 256, 0, stream>>>(xbufb, B2pk, NK2, nullptr, hbuf, NN, HID_, nullptr, 0,
                                       as2, ad2, als, ald, nullptr, nullptr);
    k_att_agg<<<NWB, 256, 0, stream>>>(rowptr, epair, als, ald, hbuf, alphap, alpha2,
                                       b2, ln2s, ln2b, xbufb);

    // ---- readout: GEMM + fused mean-pool partials ----
    k_gemm_rm<<<GB1, 256, 0, stream>>>(xbufb, Bmpk, NK2, xo, nullptr, NN, HID_, bm, 1,
                                       nullptr, nullptr, nullptr, nullptr, batch, pooled);
    k_mlp<<<1, 256, 0, stream>>>(pooled, batch, Wm1, bm1, ln3s, ln3b, Wm2, bm2, rec);
}

// Round 4
// 630.639 us; speedup vs baseline: 1.1370x; 1.0266x over previous
//
#include <hip/hip_runtime.h>
#include <hip/hip_bf16.h>
#include <cstdint>
#include <cstddef>

#define NN   50000
#define EE   800000
#define ET_  (EE + NN)      // 850000 edges incl. self-loops
#define FIN  500
#define HID_ 160
#define NC_  20
#define GG   8
#define GB1  ((NN + 63) / 64)   // 782 GEMM blocks (64 rows each)
#define NK1  16                 // layer-1 k-steps (K=500 padded to 512)
#define NK2  5                  // K=160 k-steps

typedef __attribute__((ext_vector_type(8))) short ab8;   // 8 bf16 (4 VGPRs)
typedef __attribute__((ext_vector_type(4))) float f4;    // MFMA accumulator

static __device__ __forceinline__ unsigned short f2bf(float v) {
    union { float f; uint32_t u; } c; c.f = v;
    uint32_t r = c.u + 0x7FFFu + ((c.u >> 16) & 1u);  // RNE
    return (unsigned short)(r >> 16);
}

static __device__ __forceinline__ float2 bf2f2(uint32_t u) {
    // u holds bf16 pair (lo = even ch, hi = odd ch)
    union { uint32_t u; float f; } a, b;
    a.u = u << 16;
    b.u = u & 0xffff0000u;
    return make_float2(a.f, b.f);
}

static __device__ __forceinline__ int lbound_i(const int* arr, int n, int val) {
    int lo = 0, hi = n;
    while (lo < hi) { int mid = (lo + hi) >> 1; if (arr[mid] < val) lo = mid + 1; else hi = mid; }
    return lo;
}

// ---------------- CSR build ----------------
__global__ __launch_bounds__(256) void k_hist(const int* __restrict__ ei, int* __restrict__ deg) {
    int e = blockIdx.x * 256 + threadIdx.x;
    if (e >= ET_) return;
    int d = (e < EE) ? ei[EE + e] : (e - EE);
    atomicAdd(&deg[d], 1);
}

__global__ __launch_bounds__(256) void k_scan1(const int* __restrict__ deg, int* __restrict__ rowptr,
                                               int* __restrict__ bsum) {
    __shared__ int s[256];
    int t = threadIdx.x;
    int base = blockIdx.x * 1024 + t * 4;
    int v0 = (base + 0 < NN) ? deg[base + 0] : 0;
    int v1 = (base + 1 < NN) ? deg[base + 1] : 0;
    int v2 = (base + 2 < NN) ? deg[base + 2] : 0;
    int v3 = (base + 3 < NN) ? deg[base + 3] : 0;
    int tot = v0 + v1 + v2 + v3;
    s[t] = tot;
    __syncthreads();
    for (int off = 1; off < 256; off <<= 1) {
        int y = (t >= off) ? s[t - off] : 0;
        __syncthreads();
        s[t] += y;
        __syncthreads();
    }
    int excl = s[t] - tot;
    if (t == 255) bsum[blockIdx.x] = s[255];
    if (base + 0 < NN) rowptr[base + 0] = excl;  excl += v0;
    if (base + 1 < NN) rowptr[base + 1] = excl;  excl += v1;
    if (base + 2 < NN) rowptr[base + 2] = excl;  excl += v2;
    if (base + 3 < NN) rowptr[base + 3] = excl;
}

__global__ void k_scan2(int* __restrict__ bsum, int nb) {
    int t = threadIdx.x; // single wave of 64; nb <= 64
    int v = (t < nb) ? bsum[t] : 0;
    int orig = v;
    for (int off = 1; off < 64; off <<= 1) {
        int y = __shfl_up(v, off);
        if (t >= off) v += y;
    }
    if (t < nb) bsum[t] = v - orig; // exclusive prefix
}

__global__ __launch_bounds__(256) void k_scan3(int* __restrict__ rowptr, const int* __restrict__ bsum,
                                               int* __restrict__ cursor) {
    int i = blockIdx.x * 256 + threadIdx.x;
    if (i < NN) {
        int r = rowptr[i] + bsum[i >> 10];
        rowptr[i] = r;
        cursor[i] = r;
    }
    if (i == NN) rowptr[NN] = ET_;
}

// slot payload is just the src node now (edge id no longer needed: alpha is
// emitted by the edge-ordered k_alpha kernel). Halves the scattered writes.
__global__ __launch_bounds__(256) void k_scatter(const int* __restrict__ ei, int* __restrict__ cursor,
                                                 int* __restrict__ esrc) {
    int e = blockIdx.x * 256 + threadIdx.x;
    if (e >= ET_) return;
    int s, d;
    if (e < EE) { s = ei[e]; d = ei[EE + e]; } else { s = e - EE; d = e - EE; }
    int slot = atomicAdd(&cursor[d], 1);
    esrc[slot] = s;
}

// ---------------- weight prep: fragment-packed B for all three GEMMs ----------------
// Bpk chunk (s,t,l): the 16B ab8 that lane l feeds MFMA t at k-step s.
// chunk value = W^T[n = t*16 + (l&15)][k0 = s*32 + (l>>4)*8 .. +8], zero-padded past K.
// Makes every B-fragment load in the GEMM a fully-coalesced 1KB wave burst.
__global__ __launch_bounds__(256) void k_prep_all(const float* __restrict__ W1, ab8* __restrict__ B1,
                                                  const float* __restrict__ W2, ab8* __restrict__ B2,
                                                  const float* __restrict__ Wm, ab8* __restrict__ Bm,
                                                  float* __restrict__ pooled) {
    int idx = blockIdx.x * 256 + threadIdx.x;
    if (idx < GG * HID_) pooled[idx] = 0.f;
    const int C1 = NK1 * 10 * 64;      // 10240 chunks
    const int C2 = NK2 * 10 * 64;      // 3200 chunks
    const float* W; ab8* Bo; int K, cidx;
    if (idx < C1)                { W = W1; Bo = B1; K = FIN;  cidx = idx; }
    else if (idx < C1 + C2)      { W = W2; Bo = B2; K = HID_; cidx = idx - C1; }
    else if (idx < C1 + 2 * C2)  { W = Wm; Bo = Bm; K = HID_; cidx = idx - C1 - C2; }
    else return;
    int s = cidx / 640, r = cidx % 640;
    int t = r >> 6, l = r & 63;
    int fr = l & 15, q = l >> 4;
    int n  = t * 16 + fr;
    int k0 = s * 32 + q * 8;
    unsigned short pk[8];
#pragma unroll
    for (int j = 0; j < 8; j++) {
        int k = k0 + j;
        pk[j] = (k < K) ? f2bf(W[(size_t)k * HID_ + n]) : (unsigned short)0;
    }
    Bo[cidx] = *reinterpret_cast<ab8*>(pk);
}

// ---------------- x fp32 -> fragment-packed bf16 A for layer 1 ----------------
// Apk chunk ((blk*NK1 + s)*256 + tid): the ab8 that thread tid of GEMM block blk
// feeds its MFMA at k-step s. Output writes fully coalesced; removes all f2bf
// VALU work and the 16-row scatter from the layer-1 GEMM hot loop.
// NOTE: Apk lives in the first 51.25MB of d_out (dead until later kernels).
__global__ __launch_bounds__(256) void k_conv_x(const float* __restrict__ x, ab8* __restrict__ Apk) {
    int idx = blockIdx.x * 256 + threadIdx.x;   // grid is exactly GB1*NK1*256 chunks
    int tid = idx & 255;
    int s   = (idx >> 8) & (NK1 - 1);
    int blk = idx >> 12;                         // NK1*256 = 4096
    int l = tid & 63, w = tid >> 6;
    int fr = l & 15, q = l >> 4;
    int row = blk * 64 + w * 16 + fr;
    int k0 = s * 32 + q * 8;
    unsigned short pk[8] = {0, 0, 0, 0, 0, 0, 0, 0};
    if (row < NN) {
        const float* xr = &x[(size_t)row * FIN];
        if (k0 + 8 <= FIN) {
            const float4* s4 = reinterpret_cast<const float4*>(&xr[k0]);
            float4 u = s4[0], v = s4[1];
            pk[0] = f2bf(u.x); pk[1] = f2bf(u.y); pk[2] = f2bf(u.z); pk[3] = f2bf(u.w);
            pk[4] = f2bf(v.x); pk[5] = f2bf(v.y); pk[6] = f2bf(v.z); pk[7] = f2bf(v.w);
        } else {
#pragma unroll
            for (int j = 0; j < 8; j++)
                if (k0 + j < FIN) pk[j] = f2bf(xr[k0 + j]);
        }
    }
    Apk[idx] = *reinterpret_cast<ab8*>(pk);
}

// ---------------- register-resident MFMA GEMM: C[M,160] = A[M,K] @ W[K,160] ----------------
// NO LDS, NO barriers, NO scattered loads (see round-2/3 notes). als/ald rows are
// padded to stride 8 floats so downstream gathers are float4-friendly.
template<int PKA>
static __device__ __forceinline__ void gemm_body(const void* __restrict__ Av,
                                                 const ab8* __restrict__ Bpk, int nk,
                                                 float* __restrict__ C, __hip_bfloat16* __restrict__ Cb,
                                                 int M, int K,
                                                 const float* __restrict__ bias, int act,
                                                 const float* __restrict__ asrc, const float* __restrict__ adst,
                                                 float* __restrict__ als_o, float* __restrict__ ald_o,
                                                 const int* __restrict__ batch_p, float* __restrict__ pooled) {
    int tid  = threadIdx.x;
    int lane = tid & 63;
    int w    = tid >> 6;
    int fr   = lane & 15;        // fragment row/col index
    int q    = lane >> 4;        // quad: k-subtile for inputs, row-subtile for output
    int row0 = blockIdx.x * 64;
    int arow = row0 + w * 16 + fr;   // row whose A-fragment this lane supplies
    bool rv  = arow < M;

    f4 acc[10];
#pragma unroll
    for (int t = 0; t < 10; t++) acc[t] = (f4)0.f;

    const ab8* bb  = Bpk + lane;
    const ab8* apk = reinterpret_cast<const ab8*>(Av) + (size_t)blockIdx.x * nk * 256 + tid;
    const unsigned short* Arow = (const unsigned short*)Av;

    auto loadA = [&](int s) -> ab8 {
        if (PKA) return apk[s * 256];
        ab8 a = (ab8)0;
        if (rv) a = *reinterpret_cast<const ab8*>(&Arow[(size_t)arow * K + s * 32 + q * 8]);
        return a;
    };

    ab8 bcur[10], bnx[10];
#pragma unroll
    for (int t = 0; t < 10; t++) bcur[t] = bb[t * 64];
    ab8 a0 = loadA(0);
    ab8 a1 = loadA(1);                // nk >= 5 always
    for (int s = 0; s < nk; s++) {
        if (s + 1 < nk) {
#pragma unroll
            for (int t = 0; t < 10; t++) bnx[t] = bb[((s + 1) * 10 + t) * 64];
        }
        ab8 a2 = (ab8)0;
        if (s + 2 < nk) a2 = loadA(s + 2);
#pragma unroll
        for (int t = 0; t < 10; t++)
            acc[t] = __builtin_amdgcn_mfma_f32_16x16x32_bf16(a0, bcur[t], acc[t], 0, 0, 0);
        a0 = a1; a1 = a2;
#pragma unroll
        for (int t = 0; t < 10; t++) bcur[t] = bnx[t];
    }

    // ---- fused per-node attention dots: als/ald (GAT layers), stride-8 rows ----
    if (als_o) {
        float av_s[10], av_d[10];
#pragma unroll
        for (int t = 0; t < 10; t++) { av_s[t] = asrc[t * 16 + fr]; av_d[t] = adst[t * 16 + fr]; }
#pragma unroll
        for (int i = 0; i < 4; i++) {
            int r = row0 + w * 16 + q * 4 + i;
            float ps[5], pd[5];
#pragma unroll
            for (int h = 0; h < 5; h++) {
                ps[h] = acc[2 * h][i] * av_s[2 * h] + acc[2 * h + 1][i] * av_s[2 * h + 1];
                pd[h] = acc[2 * h][i] * av_d[2 * h] + acc[2 * h + 1][i] * av_d[2 * h + 1];
            }
#pragma unroll
            for (int off = 8; off >= 1; off >>= 1)
#pragma unroll
                for (int h = 0; h < 5; h++) {
                    ps[h] += __shfl_xor(ps[h], off);
                    pd[h] += __shfl_xor(pd[h], off);
                }
            if (fr == 0 && r < M) {
#pragma unroll
                for (int h = 0; h < 5; h++) {
                    als_o[(size_t)r * 8 + h] = ps[h];
                    ald_o[(size_t)r * 8 + h] = pd[h];
                }
            }
        }
    }

    // ---- pool setup (readout GEMM): block-uniform-graph fast path ----
    int gu = -2;
    if (pooled) {
        int rhi = row0 + 63; if (rhi >= M) rhi = M - 1;
        int gl = batch_p[row0], gh = batch_p[rhi];
        gu = (gl == gh) ? gl : -1;
    }
    float psum[10];
#pragma unroll
    for (int t = 0; t < 10; t++) psum[t] = 0.f;

    // ---- epilogue: C/D layout col=lane&15, row=(lane>>4)*4+reg ----
    int rbase = row0 + w * 16 + q * 4;
#pragma unroll
    for (int t = 0; t < 10; t++) {
        int col = t * 16 + fr;
        float bv = bias ? bias[col] : 0.f;
#pragma unroll
        for (int i = 0; i < 4; i++) {
            int r = rbase + i;
            float v = acc[t][i] + bv;
            if (act) v = v > 0.f ? v : 0.01f * v;
            if (r < M) {
                if (C)  C[(size_t)r * HID_ + col] = v;
                if (Cb) *reinterpret_cast<unsigned short*>(&Cb[(size_t)r * HID_ + col]) = f2bf(v);
                if (gu >= 0) psum[t] += v;
                else if (gu == -1) atomicAdd(&pooled[batch_p[r] * HID_ + col], v);
            }
        }
    }
    if (gu >= 0) {
#pragma unroll
        for (int t = 0; t < 10; t++) {
            psum[t] += __shfl_xor(psum[t], 16);
            psum[t] += __shfl_xor(psum[t], 32);
        }
        if (q == 0) {
#pragma unroll
            for (int t = 0; t < 10; t++)
                atomicAdd(&pooled[gu * HID_ + t * 16 + fr], psum[t]);
        }
    }
}

__global__ __launch_bounds__(256) void k_gemm_pk(const void* __restrict__ Av,
                                                 const ab8* __restrict__ Bpk, int nk,
                                                 float* __restrict__ C, __hip_bfloat16* __restrict__ Cb,
                                                 int M, int K,
                                                 const float* __restrict__ bias, int act,
                                                 const float* __restrict__ asrc, const float* __restrict__ adst,
                                                 float* __restrict__ als_o, float* __restrict__ ald_o,
                                                 const int* __restrict__ batch_p, float* __restrict__ pooled) {
    gemm_body<1>(Av, Bpk, nk, C, Cb, M, K, bias, act, asrc, adst, als_o, ald_o, batch_p, pooled);
}

__global__ __launch_bounds__(256) void k_gemm_rm(const void* __restrict__ Av,
                                                 const ab8* __restrict__ Bpk, int nk,
                                                 float* __restrict__ C, __hip_bfloat16* __restrict__ Cb,
                                                 int M, int K,
                                                 const float* __restrict__ bias, int act,
                                                 const float* __restrict__ asrc, const float* __restrict__ adst,
                                                 float* __restrict__ als_o, float* __restrict__ ald_o,
                                                 const int* __restrict__ batch_p, float* __restrict__ pooled) {
    gemm_body<0>(Av, Bpk, nk, C, Cb, M, K, bias, act, asrc, adst, als_o, ald_o, batch_p, pooled);
}

// ---------- fused edge softmax + aggregation + bias + leaky + LayerNorm ----------
// One wave per destination node. Channel map: lane l owns ch {2l,2l+1}; lanes 0..15
// additionally own {128+2l,128+2l+1} (head 4). Aggregation is 4-edge unrolled
// (8 gathers in flight). Alpha emission moved to the edge-ordered k_alpha kernel;
// this kernel just stores inv[node] (coalesced 20B/node instead of a 54MB scatter).
__global__ __launch_bounds__(256) void k_att_agg(const int* __restrict__ rowptr,
                                                 const int* __restrict__ esrc,
                                                 const float* __restrict__ als, const float* __restrict__ ald,
                                                 const __hip_bfloat16* __restrict__ hmat,
                                                 float* __restrict__ alphap,      // [ET_*5] overflow scratch
                                                 float* __restrict__ invb,        // [NN*8] per-node 1/sum
                                                 const float* __restrict__ bias,
                                                 const float* __restrict__ lns, const float* __restrict__ lnb,
                                                 __hip_bfloat16* __restrict__ outb) {
    __shared__ float sExp[4][64 * 5];
    __shared__ int   sSrc[4][64];
    int wv   = threadIdx.x >> 6;
    int lane = threadIdx.x & 63;
    int node = blockIdx.x * 4 + wv;
    if (node >= NN) return;
    int start = rowptr[node], end = rowptr[node + 1];
    int deg = end - start;
    bool fits = (deg <= 64);
    float4 dd4 = *reinterpret_cast<const float4*>(&ald[(size_t)node * 8]);
    float  dd5 = ald[(size_t)node * 8 + 4];
    float ad[5] = {dd4.x, dd4.y, dd4.z, dd4.w, dd5};

    // ---- pass 1: exp(leaky(logit)), lane-parallel over edges ----
    float sm[5] = {0.f, 0.f, 0.f, 0.f, 0.f};
    for (int j = start + lane; j < end; j += 64) {
        int sy = esrc[j];
        int idx = j - start;
        if (fits) sSrc[wv][idx] = sy;
        const float* as = &als[(size_t)sy * 8];
        float4 a4 = *reinterpret_cast<const float4*>(as);
        float  a5 = as[4];
        float asv[5] = {a4.x, a4.y, a4.z, a4.w, a5};
#pragma unroll
        for (int h = 0; h < 5; h++) {
            float l = asv[h] + ad[h];
            l = l > 0.f ? l : 0.2f * l;
            float ex = __expf(fminf(l, 60.f));
            sm[h] += ex;
            if (fits) sExp[wv][idx * 5 + h] = ex;
            else      alphap[(size_t)j * 5 + h] = ex;
        }
    }
#pragma unroll
    for (int off = 32; off >= 1; off >>= 1)
#pragma unroll
        for (int h = 0; h < 5; h++) sm[h] += __shfl_xor(sm[h], off);
    float inv[5];
#pragma unroll
    for (int h = 0; h < 5; h++) inv[h] = 1.f / (sm[h] + 1e-16f);
    if (lane == 0) {
        float* ip = &invb[(size_t)node * 8];
        ip[0] = inv[0]; ip[1] = inv[1]; ip[2] = inv[2]; ip[3] = inv[3]; ip[4] = inv[4];
    }

    int h0 = lane >> 4;            // head of ch pair (2l,2l+1): 0..3
    bool lo16 = lane < 16;         // lanes 0..15 own head-4 pair {128+2l,128+2l+1}
    int c01 = 2 * lane;            // first ch pair
    int c2  = 128 + 2 * lane;      // second ch pair (lo16 only; 128..158)
    float2 A0 = make_float2(0.f, 0.f), A1 = make_float2(0.f, 0.f);
    float2 A2 = make_float2(0.f, 0.f), A3 = make_float2(0.f, 0.f);
    float2 H0 = make_float2(0.f, 0.f), H1 = make_float2(0.f, 0.f);
    float2 H2 = make_float2(0.f, 0.f), H3 = make_float2(0.f, 0.f);

    if (fits) {
        // ---- aggregation: 4-edge unrolled, ch pairs across lanes ----
        int idx = 0;
        for (; idx + 3 < deg; idx += 4) {
            int s0 = sSrc[wv][idx], s1 = sSrc[wv][idx + 1];
            int s2 = sSrc[wv][idx + 2], s3 = sSrc[wv][idx + 3];
            float w0 = sExp[wv][(idx + 0) * 5 + h0] * inv[h0];
            float w1 = sExp[wv][(idx + 1) * 5 + h0] * inv[h0];
            float w2 = sExp[wv][(idx + 2) * 5 + h0] * inv[h0];
            float w3 = sExp[wv][(idx + 3) * 5 + h0] * inv[h0];
            const unsigned short* r0 = (const unsigned short*)&hmat[(size_t)s0 * HID_];
            const unsigned short* r1 = (const unsigned short*)&hmat[(size_t)s1 * HID_];
            const unsigned short* r2 = (const unsigned short*)&hmat[(size_t)s2 * HID_];
            const unsigned short* r3 = (const unsigned short*)&hmat[(size_t)s3 * HID_];
            float2 f0 = bf2f2(*reinterpret_cast<const uint32_t*>(&r0[c01]));
            float2 f1 = bf2f2(*reinterpret_cast<const uint32_t*>(&r1[c01]));
            float2 f2 = bf2f2(*reinterpret_cast<const uint32_t*>(&r2[c01]));
            float2 f3 = bf2f2(*reinterpret_cast<const uint32_t*>(&r3[c01]));
            A0.x += w0 * f0.x; A0.y += w0 * f0.y;
            A1.x += w1 * f1.x; A1.y += w1 * f1.y;
            A2.x += w2 * f2.x; A2.y += w2 * f2.y;
            A3.x += w3 * f3.x; A3.y += w3 * f3.y;
            if (lo16) {
                float u0 = sExp[wv][(idx + 0) * 5 + 4] * inv[4];
                float u1 = sExp[wv][(idx + 1) * 5 + 4] * inv[4];
                float u2 = sExp[wv][(idx + 2) * 5 + 4] * inv[4];
                float u3 = sExp[wv][(idx + 3) * 5 + 4] * inv[4];
                float2 g0 = bf2f2(*reinterpret_cast<const uint32_t*>(&r0[c2]));
                float2 g1 = bf2f2(*reinterpret_cast<const uint32_t*>(&r1[c2]));
                float2 g2 = bf2f2(*reinterpret_cast<const uint32_t*>(&r2[c2]));
                float2 g3 = bf2f2(*reinterpret_cast<const uint32_t*>(&r3[c2]));
                H0.x += u0 * g0.x; H0.y += u0 * g0.y;
                H1.x += u1 * g1.x; H1.y += u1 * g1.y;
                H2.x += u2 * g2.x; H2.y += u2 * g2.y;
                H3.x += u3 * g3.x; H3.y += u3 * g3.y;
            }
        }
        for (; idx < deg; idx++) {
            int s0 = sSrc[wv][idx];
            float w0 = sExp[wv][idx * 5 + h0] * inv[h0];
            const unsigned short* r0 = (const unsigned short*)&hmat[(size_t)s0 * HID_];
            float2 f0 = bf2f2(*reinterpret_cast<const uint32_t*>(&r0[c01]));
            A0.x += w0 * f0.x; A0.y += w0 * f0.y;
            if (lo16) {
                float u0 = sExp[wv][idx * 5 + 4] * inv[4];
                float2 g0 = bf2f2(*reinterpret_cast<const uint32_t*>(&r0[c2]));
                H0.x += u0 * g0.x; H0.y += u0 * g0.y;
            }
        }
    } else {
        // ---- overflow path (deg > 64): exp staged in global scratch ----
        for (int j = start; j < end; j++) {
            int s0 = esrc[j];
            float w0 = alphap[(size_t)j * 5 + h0] * inv[h0];
            const unsigned short* r0 = (const unsigned short*)&hmat[(size_t)s0 * HID_];
            float2 f0 = bf2f2(*reinterpret_cast<const uint32_t*>(&r0[c01]));
            A0.x += w0 * f0.x; A0.y += w0 * f0.y;
            if (lo16) {
                float u0 = alphap[(size_t)j * 5 + 4] * inv[4];
                float2 g0 = bf2f2(*reinterpret_cast<const uint32_t*>(&r0[c2]));
                H0.x += u0 * g0.x; H0.y += u0 * g0.y;
            }
        }
    }
    float2 A = make_float2(A0.x + A1.x + A2.x + A3.x, A0.y + A1.y + A2.y + A3.y);
    float2 Hh = make_float2(H0.x + H1.x + H2.x + H3.x, H0.y + H1.y + H2.y + H3.y);

    // ---- bias + leaky(0.01) + LayerNorm ----
    float2 bb = *reinterpret_cast<const float2*>(&bias[c01]);
    float v0 = A.x + bb.x;  v0 = v0 > 0.f ? v0 : 0.01f * v0;
    float v1 = A.y + bb.y;  v1 = v1 > 0.f ? v1 : 0.01f * v1;
    float v2 = 0.f, v3 = 0.f;
    if (lo16) {
        float2 b2 = *reinterpret_cast<const float2*>(&bias[c2]);
        v2 = Hh.x + b2.x; v2 = v2 > 0.f ? v2 : 0.01f * v2;
        v3 = Hh.y + b2.y; v3 = v3 > 0.f ? v3 : 0.01f * v3;
    }
    float s  = v0 + v1 + v2 + v3;
    float sq = v0 * v0 + v1 * v1 + v2 * v2 + v3 * v3;
#pragma unroll
    for (int off = 32; off >= 1; off >>= 1) {
        s  += __shfl_xor(s, off);
        sq += __shfl_xor(sq, off);
    }
    float m = s * (1.f / 160.f);
    float r = rsqrtf(sq * (1.f / 160.f) - m * m + 1e-5f);
    size_t ob = (size_t)node * HID_;
    {
        float2 sc = *reinterpret_cast<const float2*>(&lns[c01]);
        float2 bi = *reinterpret_cast<const float2*>(&lnb[c01]);
        uint32_t pk = (uint32_t)f2bf((v0 - m) * r * sc.x + bi.x)
                    | ((uint32_t)f2bf((v1 - m) * r * sc.y + bi.y) << 16);
        *reinterpret_cast<uint32_t*>(&outb[ob + c01]) = pk;
    }
    if (lo16) {
        float2 sc = *reinterpret_cast<const float2*>(&lns[c2]);
        float2 bi = *reinterpret_cast<const float2*>(&lnb[c2]);
        uint32_t pk = (uint32_t)f2bf((v2 - m) * r * sc.x + bi.x)
                    | ((uint32_t)f2bf((v3 - m) * r * sc.y + bi.y) << 16);
        *reinterpret_cast<uint32_t*>(&outb[ob + c2]) = pk;
    }
}

// ---------- edge-ordered alpha emission: fully coalesced 20B/edge writes ----------
// Recomputes the identical exp(leaky(als+ald)) and multiplies by the stored inv
// (same float values, same op order as the old in-kernel scatter -> bit-identical),
// but iterates in edge-id order so alpha_out writes stream instead of scattering.
__global__ __launch_bounds__(256) void k_alpha(const int* __restrict__ ei,
                                               const float* __restrict__ als, const float* __restrict__ ald,
                                               const float* __restrict__ invb,
                                               float* __restrict__ alpha_out) {
    int e = blockIdx.x * 256 + threadIdx.x;
    if (e >= ET_) return;
    int s, d;
    if (e < EE) { s = ei[e]; d = ei[EE + e]; } else { s = e - EE; d = e - EE; }
    const float* as = &als[(size_t)s * 8];
    float4 a4 = *reinterpret_cast<const float4*>(as);
    float  a5 = as[4];
    float asv[5] = {a4.x, a4.y, a4.z, a4.w, a5};
    const float* adp = &ald[(size_t)d * 8];
    float4 d4 = *reinterpret_cast<const float4*>(adp);
    float  d5 = adp[4];
    float adv[5] = {d4.x, d4.y, d4.z, d4.w, d5};
    const float* ip = &invb[(size_t)d * 8];
    float4 i4 = *reinterpret_cast<const float4*>(ip);
    float  i5 = ip[4];
    float ivv[5] = {i4.x, i4.y, i4.z, i4.w, i5};
    float* ao = &alpha_out[(size_t)e * 5];
#pragma unroll
    for (int h = 0; h < 5; h++) {
        float l = asv[h] + adv[h];
        l = l > 0.f ? l : 0.2f * l;
        float ex = __expf(fminf(l, 60.f));
        ao[h] = ex * ivv[h];
    }
}

// ---------------- readout MLP (single block) ----------------
__global__ __launch_bounds__(256) void k_mlp(const float* __restrict__ pooled, const int* __restrict__ batch,
                                             const float* __restrict__ W1, const float* __restrict__ b1,
                                             const float* __restrict__ lns, const float* __restrict__ lnb,
                                             const float* __restrict__ W2, const float* __restrict__ b2,
                                             float* __restrict__ rec) {
    __shared__ float P[GG][HID_];
    __shared__ float Z[GG][HID_];
    __shared__ float mu[GG], rr[GG], ic[GG];
    int t = threadIdx.x;
    if (t < GG) {
        int lo = lbound_i(batch, NN, t), hi = lbound_i(batch, NN, t + 1);
        ic[t] = 1.f / fmaxf((float)(hi - lo), 1.f);
    }
    __syncthreads();
    for (int i = t; i < GG * HID_; i += 256) P[i / HID_][i % HID_] = pooled[i] * ic[i / HID_];
    __syncthreads();
    for (int i = t; i < GG * HID_; i += 256) {
        int g = i / HID_, j = i % HID_;
        float acc = b1[j];
        for (int k = 0; k < HID_; k++) acc += P[g][k] * W1[k * HID_ + j];
        Z[g][j] = acc;
    }
    __syncthreads();
    if (t < GG) {
        float s = 0.f, sq = 0.f;
        for (int k = 0; k < HID_; k++) { float z = Z[t][k]; s += z; sq += z * z; }
        float m = s / (float)HID_;
        mu[t] = m;
        rr[t] = rsqrtf(sq / (float)HID_ - m * m + 1e-5f);
    }
    __syncthreads();
    for (int i = t; i < GG * HID_; i += 256) {
        int g = i / HID_, j = i % HID_;
        float z = (Z[g][j] - mu[g]) * rr[g] * lns[j] + lnb[j];
        Z[g][j] = fmaxf(z, 0.f);
    }
    __syncthreads();
    for (int i = t; i < GG * NC_; i += 256) {
        int g = i / NC_, j = i % NC_;
        float acc = b2[j];
        for (int k = 0; k < HID_; k++) acc += Z[g][k] * W2[k * NC_ + j];
        rec[g * NC_ + j] = acc;
    }
}

extern "C" void kernel_launch(void* const* d_in, const int* in_sizes, int n_in,
                              void* d_out, int out_size, void* d_ws, size_t ws_size,
                              hipStream_t stream) {
    const float* x    = (const float*)d_in[0];
    const int*   ei   = (const int*)d_in[1];
    const int*   batch= (const int*)d_in[2];
    const float* W1   = (const float*)d_in[3];
    const float* as1  = (const float*)d_in[4];
    const float* ad1  = (const float*)d_in[5];
    const float* b1   = (const float*)d_in[6];
    const float* ln1s = (const float*)d_in[7];
    const float* ln1b = (const float*)d_in[8];
    const float* W2   = (const float*)d_in[9];
    const float* as2  = (const float*)d_in[10];
    const float* ad2  = (const float*)d_in[11];
    const float* b2   = (const float*)d_in[12];
    const float* ln2s = (const float*)d_in[13];
    const float* ln2b = (const float*)d_in[14];
    const float* Wm   = (const float*)d_in[15];
    const float* bm   = (const float*)d_in[16];
    const float* Wm1  = (const float*)d_in[17];
    const float* bm1  = (const float*)d_in[18];
    const float* ln3s = (const float*)d_in[19];
    const float* ln3b = (const float*)d_in[20];
    const float* Wm2  = (const float*)d_in[21];
    const float* bm2  = (const float*)d_in[22];

    float* out    = (float*)d_out;
    float* xo     = out;                              // N*160
    float* rec    = out + (size_t)NN * HID_;          // 8*20
    float* alpha1 = rec + GG * NC_;                   // ET*5
    float* alpha2 = alpha1 + (size_t)ET_ * 5;         // ET*5

    char* w = (char*)d_ws;
    auto carve = [&](size_t bytes) { char* p = w; w += (bytes + 255) & ~(size_t)255; return p; };
    int*   deg    = (int*)carve((size_t)NN * 4);
    int*   rowptr = (int*)carve((size_t)(NN + 1) * 4);
    int*   cursor = (int*)carve((size_t)NN * 4);
    int*   esrc   = (int*)carve((size_t)ET_ * 4);
    int*   bsum   = (int*)carve(64 * 4);
    __hip_bfloat16* hbuf  = (__hip_bfloat16*)carve((size_t)NN * HID_ * 2);
    __hip_bfloat16* xbufb = (__hip_bfloat16*)carve((size_t)NN * HID_ * 2);
    float* alphap = (float*)carve((size_t)ET_ * 5 * 4);
    float* als    = (float*)carve((size_t)NN * 8 * 4);
    float* ald    = (float*)carve((size_t)NN * 8 * 4);
    float* invb   = (float*)carve((size_t)NN * 8 * 4);
    float* pooled = (float*)carve((size_t)GG * HID_ * 4);
    ab8*   B1pk   = (ab8*)carve((size_t)NK1 * 10 * 64 * 16);     // 160 KB
    ab8*   B2pk   = (ab8*)carve((size_t)NK2 * 10 * 64 * 16);     // 50 KB
    ab8*   Bmpk   = (ab8*)carve((size_t)NK2 * 10 * 64 * 16);     // 50 KB
    // Apk (51.25MB) lives in d_out: that region is dead until k_att_agg/readout,
    // which all run after the layer-1 GEMM finishes reading Apk.
    ab8*   Apk    = (ab8*)d_out;                                 // GB1*NK1*256*16 B

    // ---- CSR by destination (rebuilt every call; ws is re-poisoned) ----
    hipMemsetAsync(deg, 0, (size_t)NN * 4, stream);
    k_hist<<<(ET_ + 255) / 256, 256, 0, stream>>>(ei, deg);
    int nb = (NN + 1023) / 1024;
    k_scan1<<<nb, 256, 0, stream>>>(deg, rowptr, bsum);
    k_scan2<<<1, 64, 0, stream>>>(bsum, nb);
    k_scan3<<<(NN + 1 + 255) / 256, 256, 0, stream>>>(rowptr, bsum, cursor);
    k_scatter<<<(ET_ + 255) / 256, 256, 0, stream>>>(ei, cursor, esrc);

    // ---- weight prep (fragment-packed B; also zeroes pooled) + packed-A conversion ----
    const int PREP = NK1 * 10 * 64 + 2 * NK2 * 10 * 64;  // 16640 chunk threads
    k_prep_all<<<(PREP + 255) / 256, 256, 0, stream>>>(W1, B1pk, W2, B2pk, Wm, Bmpk, pooled);
    k_conv_x<<<GB1 * NK1, 256, 0, stream>>>(x, Apk);

    const int NWB = (NN + 3) / 4;         // wave-per-node blocks (4 waves/block)
    const int EB  = (ET_ + 255) / 256;    // edge-parallel blocks

    // ---- layer 1 ----
    k_gemm_pk<<<GB1, 256, 0, stream>>>(Apk, B1pk, NK1, nullptr, hbuf, NN, FIN, nullptr, 0,
                                       as1, ad1, als, ald, nullptr, nullptr);
    k_att_agg<<<NWB, 256, 0, stream>>>(rowptr, esrc, als, ald, hbuf, alphap, invb,
                                       b1, ln1s, ln1b, xbufb);
    k_alpha<<<EB, 256, 0, stream>>>(ei, als, ald, invb, alpha1);

    // ---- layer 2 ----
    k_gemm_rm<<<GB1, 256, 0, stream>>>(xbufb, B2pk, NK2, nullptr, hbuf, NN, HID_, nullptr, 0,
                                       as2, ad2, als, ald, nullptr, nullptr);
    k_att_agg<<<NWB, 256, 0, stream>>>(rowptr, esrc, als, ald, hbuf, alphap, invb,
                                       b2, ln2s, ln2b, xbufb);
    k_alpha<<<EB, 256, 0, stream>>>(ei, als, ald, invb, alpha2);

    // ---- readout: GEMM + fused mean-pool partials ----
    k_gemm_rm<<<GB1, 256, 0, stream>>>(xbufb, Bmpk, NK2, xo, nullptr, NN, HID_, bm, 1,
                                       nullptr, nullptr, nullptr, nullptr, batch, pooled);
    k_mlp<<<1, 256, 0, stream>>>(pooled, batch, Wm1, bm1, ln3s, ln3b, Wm2, bm2, rec);
}